// Round 2
// baseline (1496.195 us; speedup 1.0000x reference)
//
#include <hip/hip_runtime.h>
#include <hip/hip_fp16.h>

typedef _Float16 f16;
typedef _Float16 f16x8 __attribute__((ext_vector_type(8)));
typedef _Float16 f16x2 __attribute__((ext_vector_type(2)));
typedef float f32x4 __attribute__((ext_vector_type(4)));

static constexpr int kB  = 16;
static constexpr int kLC = 512;

// gate input scales folded into weights: sigm(x)=1/(1+exp2(-x*log2e)); tanh(y)=1-2/(1+exp2(y*2log2e))
#define S_RZ (-1.4426950408889634f)
#define S_N  ( 2.8853900817779268f)

// ---------------- helpers ----------------
__device__ __forceinline__ float sigm(float x) { return 1.f / (1.f + __expf(-x)); }
__device__ __forceinline__ float tanhfast(float x) {
  float xc = fminf(fmaxf(x, -15.f), 15.f);
  float e = __expf(2.f * xc);
  return (e - 1.f) / (e + 1.f);
}
__device__ __forceinline__ void load_lds_16(const void* g, void* l) {
  __builtin_amdgcn_global_load_lds(
      (const __attribute__((address_space(1))) void*)g,
      (__attribute__((address_space(3))) void*)(unsigned)(unsigned long long)l,
      16, 0, 0);
}

// ---------------- conversion kernels ----------------
__global__ void cvt_flat(const float* __restrict__ in, f16* __restrict__ out, int n) {
  int i = blockIdx.x * 256 + threadIdx.x;
  if (i < n) out[i] = (f16)in[i];
}
__global__ void cvt_ctx(const float* __restrict__ in, f16* __restrict__ out) {
  int i = blockIdx.x * 256 + threadIdx.x;
  int r = i >> 8, c = i & 255;
  out[r * 512 + c] = (f16)in[i];
}
__global__ void cvt_tr(const float* __restrict__ in, f16* __restrict__ out, int R, int C) {
  __shared__ float t[32][33];
  int nbc = C >> 5;
  int c0 = (blockIdx.x % nbc) << 5;
  int r0 = (blockIdx.x / nbc) << 5;
  int tx = threadIdx.x & 31, ty = threadIdx.x >> 5;
  #pragma unroll
  for (int rr = 0; rr < 32; rr += 8)
    t[ty + rr][tx] = in[(size_t)(r0 + ty + rr) * C + c0 + tx];
  __syncthreads();
  #pragma unroll
  for (int rr = 0; rr < 32; rr += 8)
    out[(size_t)(c0 + ty + rr) * R + r0 + tx] = (f16)t[tx][ty + rr];
}

// Wih rows permuted into c'-layout (xp layout) + scaled.
// c' = w*96 + l15*6 + s ; s -> g=s>>1, jj=s&1 ; j = w*32 + jj*16 + l15 ; orig row = g*256+j
__global__ void cvt_wih_g(const float* __restrict__ Wih, f16* __restrict__ out) {
  const int cp = blockIdx.x;           // 0..767
  const int w = cp / 96, r = cp % 96, l15 = r / 6, s = r % 6;
  const int g = s >> 1, jj = s & 1;
  const int orig = g * 256 + w * 32 + jj * 16 + l15;
  const float sc = (g < 2) ? S_RZ : S_N;
  const float* src = Wih + (size_t)orig * 512;
  f16* dst = out + (size_t)cp * 512;
  for (int k = threadIdx.x; k < 512; k += 256) dst[k] = (f16)(sc * src[k]);
}
// Whh rows permuted into c''-layout (GRU B-frag layout) + scaled.
// c'' = w*96 + s*16 + l15
__global__ void cvt_whh_g(const float* __restrict__ Whh, f16* __restrict__ out) {
  const int cpp = blockIdx.x;          // 0..767
  const int w = cpp / 96, r = cpp % 96, s = r / 16, l15 = r % 16;
  const int g = s >> 1, jj = s & 1;
  const int orig = g * 256 + w * 32 + jj * 16 + l15;
  const float sc = (g < 2) ? S_RZ : S_N;
  const float* src = Whh + (size_t)orig * 256;
  f16* dst = out + (size_t)cpp * 256;
  dst[threadIdx.x] = (f16)(sc * src[threadIdx.x]);
}
// bias_g[c'] = sc*(bih[orig] + (g<2)*bhh[orig]);  bhh_ng[c''] = (g==2)? S_N*bhh[orig] : 0
__global__ void cvt_bias_g(const float* __restrict__ bih, const float* __restrict__ bhh,
                           float* __restrict__ bias_g, float* __restrict__ bhh_ng) {
  const int i = threadIdx.x + blockIdx.x * 256;   // 0..767
  {
    const int w = i / 96, r = i % 96, l15 = r / 6, s = r % 6;
    const int g = s >> 1, jj = s & 1;
    const int orig = g * 256 + w * 32 + jj * 16 + l15;
    const float sc = (g < 2) ? S_RZ : S_N;
    bias_g[i] = sc * (bih[orig] + ((g < 2) ? bhh[orig] : 0.f));
  }
  {
    const int w = i / 96, r = i % 96, s = r / 16, l15 = r % 16;
    const int g = s >> 1, jj = s & 1;
    const int orig = g * 256 + w * 32 + jj * 16 + l15;
    bhh_ng[i] = (g == 2) ? S_N * bhh[orig] : 0.f;
  }
}
// zero out rows past context_len
__global__ void mask_out(float* __restrict__ out, const int* __restrict__ clen) {
  const int row = blockIdx.x;          // b*512+t
  const int b = row >> 9, t = row & 511;
  if (t >= clen[b]) out[(size_t)row * 256 + threadIdx.x] = 0.f;
}

// ---------------- MFMA f16 GEMM (128x128 tile, BK=32) ----------------
// A [M,K] f16 (lda), B [N,K] f16 (ldb) -> C[M,N]
// EPI 0: Cf = acc + bias[col] (f32)
// EPI 1: Ch = f16( Gin * sigmoid(acc + bias[col]) )
// EPI 2: Ch = f16( acc + bias[col] )
template <int EPI>
__global__ __launch_bounds__(256, 2) void gemm_nt(
    const f16* __restrict__ A, int lda,
    const f16* __restrict__ B, int ldb,
    const float* __restrict__ bias,
    float* __restrict__ Cf, f16* __restrict__ Ch, const f16* __restrict__ Gin,
    int M, int N, int K) {
  __shared__ f16 As[2][128 * 32];
  __shared__ f16 Bs[2][128 * 32];
  const int tiles_n = N >> 7;
  const int bm = (blockIdx.x / tiles_n) << 7;
  const int bn = (blockIdx.x % tiles_n) << 7;
  const int tid = threadIdx.x, wv = tid >> 6, lane = tid & 63;
  const int lr = lane & 15, lk = lane >> 4;
  const int wm = (wv >> 1) << 6, wn = (wv & 1) << 6;
  const int srow = lane >> 2;
  const int scol = (lane & 3) << 3;
  f32x4 acc[4][4] = {};

  auto stage = [&](int buf, int kt) {
    const int k0 = kt << 5;
    #pragma unroll
    for (int c = 0; c < 2; ++c) {
      const int row = ((wv * 2 + c) << 4) + srow;
      load_lds_16(A + (size_t)(bm + row) * lda + k0 + scol,
                  &As[buf][(wv * 2 + c) * 512]);
      load_lds_16(B + (size_t)(bn + row) * ldb + k0 + scol,
                  &Bs[buf][(wv * 2 + c) * 512]);
    }
  };

  const int NT = K >> 5;
  stage(0, 0);
  for (int kt = 0; kt < NT; ++kt) {
    const int buf = kt & 1;
    __syncthreads();
    if (kt + 1 < NT) stage(buf ^ 1, kt + 1);
    f16x8 af[4], bf[4];
    #pragma unroll
    for (int i = 0; i < 4; ++i)
      af[i] = *(const f16x8*)&As[buf][(wm + i * 16 + lr) * 32 + lk * 8];
    #pragma unroll
    for (int i = 0; i < 4; ++i)
      bf[i] = *(const f16x8*)&Bs[buf][(wn + i * 16 + lr) * 32 + lk * 8];
    #pragma unroll
    for (int mi = 0; mi < 4; ++mi)
      #pragma unroll
      for (int ni = 0; ni < 4; ++ni)
        acc[mi][ni] = __builtin_amdgcn_mfma_f32_16x16x32_f16(af[mi], bf[ni], acc[mi][ni], 0, 0, 0);
    __syncthreads();
  }

  const int crow0 = bm + wm + lk * 4;
  const int ccol0 = bn + wn + lr;
  #pragma unroll
  for (int mi = 0; mi < 4; ++mi) {
    #pragma unroll
    for (int ni = 0; ni < 4; ++ni) {
      const int col = ccol0 + ni * 16;
      const float bv = bias[col];
      #pragma unroll
      for (int j = 0; j < 4; ++j) {
        const int row = crow0 + mi * 16 + j;
        const float v = acc[mi][ni][j] + bv;
        if constexpr (EPI == 0) {
          Cf[(size_t)row * N + col] = v;
        } else if constexpr (EPI == 1) {
          const float rin = (float)Gin[(size_t)row * N + col];
          Ch[(size_t)row * N + col] = (f16)(rin * sigm(v));
        } else {
          Ch[(size_t)row * N + col] = (f16)v;
        }
      }
    }
  }
}

// ---------------- fused additive attention ----------------
__global__ __launch_bounds__(256) void attn_kernel(
    const float* __restrict__ cd, const float* __restrict__ qd,
    const float* __restrict__ qrep, const float* __restrict__ Ws,
    const float* __restrict__ bsp, const float* __restrict__ qmask,
    f16* __restrict__ rnn_h) {
  const int b = blockIdx.x >> 4;
  const int pc = blockIdx.x & 15;
  __shared__ f16 qd_s[64][264];
  __shared__ float ws_s[256];
  __shared__ float cd_s[256];
  __shared__ float sc_s[64];
  __shared__ float msk[64];
  const int tid = threadIdx.x;
  const float* qdb = qd + (size_t)b * 64 * 256;
  for (int i = tid; i < 64 * 256; i += 256) qd_s[i >> 8][i & 255] = (f16)qdb[i];
  ws_s[tid] = Ws[tid];
  if (tid < 64) msk[tid] = qmask[b * 64 + tid];
  __syncthreads();
  const float bsv = bsp[0];
  const float* qr = qrep + (size_t)b * 64 * 256;
  const int q = tid >> 2, l4 = tid & 3;
  for (int pi = 0; pi < 32; ++pi) {
    const int p = (pc << 5) + pi;
    cd_s[tid] = cd[((size_t)b * 512 + p) * 256 + tid];
    __syncthreads();
    float s = 0.f;
    #pragma unroll 2
    for (int jj = 0; jj < 16; ++jj) {
      const int h0 = (l4 << 2) + (jj << 4);
      #pragma unroll
      for (int e = 0; e < 4; ++e) {
        const int hh = h0 + e;
        s += ws_s[hh] * tanhfast(cd_s[hh] + (float)qd_s[q][hh]);
      }
    }
    s += __shfl_xor(s, 1);
    s += __shfl_xor(s, 2);
    if (l4 == 0) sc_s[q] = (msk[q] > 0.f) ? (s + bsv) : -1e30f;
    __syncthreads();
    if (tid < 64) {
      float v = sc_s[tid], m = v;
      #pragma unroll
      for (int o = 32; o; o >>= 1) m = fmaxf(m, __shfl_xor(m, o));
      const float e = __expf(v - m);
      float su = e;
      #pragma unroll
      for (int o = 32; o; o >>= 1) su += __shfl_xor(su, o);
      sc_s[tid] = e / su;
    }
    __syncthreads();
    float a = 0.f;
    #pragma unroll 8
    for (int q2 = 0; q2 < 64; ++q2) a = fmaf(sc_s[q2], qr[q2 * 256 + tid], a);
    rnn_h[(((size_t)b * 512 + p) << 9) + 256 + tid] = (f16)a;
  }
}

// ---------------- GRU: single block, MFMA recurrence ----------------
// M=16 batches, N=768 (8 waves x 6 subtiles of 16), K=256, Whh in VGPRs.
// xp: [8192][768] f16, c'-layout (lane's 6 gate values contiguous, 12B).
// h: double-buffered LDS [16][256] f16, XOR-swizzled byte ^= (b&7)<<4.
__global__ __launch_bounds__(512, 2) void gru_mfma(
    const f16* __restrict__ xp, const f16* __restrict__ Whh_g,
    const float* __restrict__ bhh_ng, float* __restrict__ out) {
  const int tid = threadIdx.x;
  const int wv = tid >> 6, l = tid & 63, l15 = l & 15, lh = l >> 4;
  __shared__ char hs[2][16 * 512];
  for (int i = tid; i < 16 * 512 / 4; i += 512) ((float*)hs[0])[i] = 0.f;

  // Whh B-fragments: wb[s][kt], row c'' = wv*96 + s*16 + l15, k = kt*32 + lh*8
  f16x8 wb[6][8];
  #pragma unroll
  for (int s = 0; s < 6; ++s)
    #pragma unroll
    for (int kt = 0; kt < 8; ++kt)
      wb[s][kt] = *(const f16x8*)(Whh_g + (size_t)(wv * 96 + s * 16 + l15) * 256 + kt * 32 + lh * 8);

  const float bhn0 = bhh_ng[wv * 96 + 64 + l15];
  const float bhn1 = bhh_ng[wv * 96 + 80 + l15];

  unsigned h2[4];                       // h as f16x2 per batch-reg (jj0,jj1)
  #pragma unroll
  for (int j = 0; j < 4; ++j) h2[j] = 0u;

  const int cpo = wv * 96 + l15 * 6;    // c' base for this lane
  uint3 xq[4];
  #pragma unroll
  for (int j = 0; j < 4; ++j)
    xq[j] = *(const uint3*)(xp + ((size_t)(lh * 4 + j) * 512 + 0) * 768 + cpo);
  __syncthreads();

  for (int t = 0; t < 512; ++t) {
    const int cur = t & 1;
    // acc init: r,z from xp; n from bhh_n; save xn
    f32x4 acc[6];
    unsigned xnp[4];
    #pragma unroll
    for (int j = 0; j < 4; ++j) {
      f16x2 rr = __builtin_bit_cast(f16x2, xq[j].x);
      f16x2 zz = __builtin_bit_cast(f16x2, xq[j].y);
      acc[0][j] = (float)rr.x; acc[1][j] = (float)rr.y;
      acc[2][j] = (float)zz.x; acc[3][j] = (float)zz.y;
      xnp[j] = xq[j].z;
      acc[4][j] = bhn0;        acc[5][j] = bhn1;
    }
    // prefetch next step's xp (reuse regs; clamp last)
    {
      const int tn = (t + 1 < 512) ? t + 1 : 511;
      #pragma unroll
      for (int j = 0; j < 4; ++j)
        xq[j] = *(const uint3*)(xp + ((size_t)(lh * 4 + j) * 512 + tn) * 768 + cpo);
    }
    // MFMA over K
    const char* hb = hs[cur];
    #pragma unroll
    for (int kt = 0; kt < 8; ++kt) {
      const int off = (l15 * 512 + kt * 64 + lh * 16) ^ ((l15 & 7) << 4);
      f16x8 a = *(const f16x8*)(hb + off);
      #pragma unroll
      for (int s = 0; s < 6; ++s)
        acc[s] = __builtin_amdgcn_mfma_f32_16x16x32_f16(a, wb[s][kt], acc[s], 0, 0, 0);
    }
    // gates + h update + stores
    char* hw = hs[cur ^ 1];
    #pragma unroll
    for (int j = 0; j < 4; ++j) {
      const int b = lh * 4 + j;
      const f16x2 hold = __builtin_bit_cast(f16x2, h2[j]);
      const f16x2 xn = __builtin_bit_cast(f16x2, xnp[j]);
      float hn0, hn1;
      {
        const float r = __builtin_amdgcn_rcpf(1.f + __builtin_amdgcn_exp2f(acc[0][j]));
        const float z = __builtin_amdgcn_rcpf(1.f + __builtin_amdgcn_exp2f(acc[2][j]));
        const float yy = fmaf(r, acc[4][j], (float)xn.x);
        const float n = fmaf(-2.f, __builtin_amdgcn_rcpf(1.f + __builtin_amdgcn_exp2f(yy)), 1.f);
        hn0 = fmaf(z, (float)hold.x - n, n);
        out[((size_t)b * 512 + t) * 256 + wv * 32 + l15] = hn0;
      }
      {
        const float r = __builtin_amdgcn_rcpf(1.f + __builtin_amdgcn_exp2f(acc[1][j]));
        const float z = __builtin_amdgcn_rcpf(1.f + __builtin_amdgcn_exp2f(acc[3][j]));
        const float yy = fmaf(r, acc[5][j], (float)xn.y);
        const float n = fmaf(-2.f, __builtin_amdgcn_rcpf(1.f + __builtin_amdgcn_exp2f(yy)), 1.f);
        hn1 = fmaf(z, (float)hold.y - n, n);
        out[((size_t)b * 512 + t) * 256 + wv * 32 + 16 + l15] = hn1;
      }
      const f16 h0h = (f16)hn0, h1h = (f16)hn1;
      h2[j] = __builtin_bit_cast(unsigned, (f16x2){h0h, h1h});
      *(f16*)(hw + ((b * 512 + (wv * 32 + l15) * 2) ^ ((b & 7) << 4))) = h0h;
      *(f16*)(hw + ((b * 512 + (wv * 32 + 16 + l15) * 2) ^ ((b & 7) << 4))) = h1h;
    }
    __syncthreads();
  }
}

// ---------------- launch ----------------
extern "C" void kernel_launch(void* const* d_in, const int* in_sizes, int n_in,
                              void* d_out, int out_size, void* d_ws, size_t ws_size,
                              hipStream_t stream) {
  const float* ctx   = (const float*)d_in[0];
  const float* qrep  = (const float*)d_in[1];
  const int*   clen  = (const int*)d_in[2];
  const float* qmask = (const float*)d_in[3];
  const float* Wc    = (const float*)d_in[4];
  const float* bc    = (const float*)d_in[5];
  const float* Wq    = (const float*)d_in[6];
  const float* bq    = (const float*)d_in[7];
  const float* Ws    = (const float*)d_in[8];
  const float* bs    = (const float*)d_in[9];
  const float* Wg    = (const float*)d_in[10];
  const float* bg    = (const float*)d_in[11];
  const float* Wih   = (const float*)d_in[12];
  const float* Whh   = (const float*)d_in[13];
  const float* bih   = (const float*)d_in[14];
  const float* bhh   = (const float*)d_in[15];
  float* out = (float*)d_out;

  char* w = (char*)d_ws;
  auto alloc = [&](size_t bytes) -> void* {
    void* p = (void*)w;
    w += (bytes + 255) & ~(size_t)255;
    return p;
  };
  const int M = kB * kLC;                 // 8192
  float* cd     = (float*)alloc((size_t)M * 256 * 4);
  float* qd     = (float*)alloc((size_t)1024 * 256 * 4);
  f16* rnn_h    = (f16*)alloc((size_t)M * 512 * 2);
  f16* q_h      = (f16*)alloc((size_t)1024 * 256 * 2);
  f16* g_h      = (f16*)alloc((size_t)M * 512 * 2);
  f16* xp_h     = (f16*)alloc((size_t)M * 768 * 2);
  f16* Wct_h    = (f16*)alloc((size_t)256 * 256 * 2);
  f16* Wqt_h    = (f16*)alloc((size_t)256 * 256 * 2);
  f16* Wgt_h    = (f16*)alloc((size_t)512 * 512 * 2);
  f16* Wih_g    = (f16*)alloc((size_t)768 * 512 * 2);
  f16* Whh_g    = (f16*)alloc((size_t)768 * 256 * 2);
  float* bias_g = (float*)alloc(768 * 4);
  float* bhh_ng = (float*)alloc(768 * 4);

  // conversions
  cvt_ctx   <<<M, 256, 0, stream>>>(ctx, rnn_h);
  cvt_flat  <<<1024, 256, 0, stream>>>(qrep, q_h, 1024 * 256);
  cvt_tr    <<<64, 256, 0, stream>>>(Wc, Wct_h, 256, 256);
  cvt_tr    <<<64, 256, 0, stream>>>(Wq, Wqt_h, 256, 256);
  cvt_tr    <<<256, 256, 0, stream>>>(Wg, Wgt_h, 512, 512);
  cvt_wih_g <<<768, 256, 0, stream>>>(Wih, Wih_g);
  cvt_whh_g <<<768, 256, 0, stream>>>(Whh, Whh_g);
  cvt_bias_g<<<3, 256, 0, stream>>>(bih, bhh, bias_g, bhh_ng);

  // cd = ctx @ Wc + bc ; qd = q @ Wq + bq
  gemm_nt<0><<<(M / 128) * (256 / 128), 256, 0, stream>>>(
      rnn_h, 512, Wct_h, 256, bc, cd, nullptr, nullptr, M, 256, 256);
  gemm_nt<0><<<(1024 / 128) * (256 / 128), 256, 0, stream>>>(
      q_h, 256, Wqt_h, 256, bq, qd, nullptr, nullptr, 1024, 256, 256);

  // attention -> rnn_h[:, 256:512]
  attn_kernel<<<256, 256, 0, stream>>>(cd, qd, qrep, Ws, bs, qmask, rnn_h);

  // g = rnn_in * sigmoid(rnn_in @ Wg + bg)
  gemm_nt<1><<<(M / 128) * (512 / 128), 256, 0, stream>>>(
      rnn_h, 512, Wgt_h, 512, bg, nullptr, g_h, rnn_h, M, 512, 512);

  // xp = f16( g @ Wih_g.T + bias_g )   (permuted, scaled gate inputs)
  gemm_nt<2><<<(M / 128) * (768 / 128), 256, 0, stream>>>(
      g_h, 512, Wih_g, 512, bias_g, nullptr, xp_h, nullptr, M, 768, 512);

  // GRU recurrence (single block, MFMA)
  gru_mfma<<<1, 512, 0, stream>>>(xp_h, Whh_g, bhh_ng, out);

  // mask t >= len
  mask_out<<<M, 256, 0, stream>>>(out, clen);
}

// Round 4
// 1424.402 us; speedup vs baseline: 1.0504x; 1.0504x over previous
//
#include <hip/hip_runtime.h>
#include <hip/hip_fp16.h>

typedef _Float16 f16;
typedef _Float16 f16x8 __attribute__((ext_vector_type(8)));
typedef _Float16 f16x2 __attribute__((ext_vector_type(2)));
typedef float f32x4 __attribute__((ext_vector_type(4)));

static constexpr int kB  = 16;
static constexpr int kLC = 512;

// gate scales folded into weights: sigm(x)=1/(1+exp2(-x*log2e)); tanh(y)=1-2/(1+exp2(y*2log2e))
#define S_RZ (-1.4426950408889634f)
#define S_N  ( 2.8853900817779268f)

// ---------------- helpers ----------------
__device__ __forceinline__ float sigm(float x) { return 1.f / (1.f + __expf(-x)); }
__device__ __forceinline__ float tanhfast(float x) {
  float xc = fminf(fmaxf(x, -15.f), 15.f);
  float e = __expf(2.f * xc);
  return (e - 1.f) / (e + 1.f);
}
__device__ __forceinline__ void load_lds_16(const void* g, void* l) {
  __builtin_amdgcn_global_load_lds(
      (const __attribute__((address_space(1))) void*)g,
      (__attribute__((address_space(3))) void*)(unsigned)(unsigned long long)l,
      16, 0, 0);
}

// ---------------- conversion kernels ----------------
__global__ void cvt_flat(const float* __restrict__ in, f16* __restrict__ out, int n) {
  int i = blockIdx.x * 256 + threadIdx.x;
  if (i < n) out[i] = (f16)in[i];
}
__global__ void cvt_ctx(const float* __restrict__ in, f16* __restrict__ out) {
  int i = blockIdx.x * 256 + threadIdx.x;
  int r = i >> 8, c = i & 255;
  out[r * 512 + c] = (f16)in[i];
}
__global__ void cvt_tr(const float* __restrict__ in, f16* __restrict__ out, int R, int C) {
  __shared__ float t[32][33];
  int nbc = C >> 5;
  int c0 = (blockIdx.x % nbc) << 5;
  int r0 = (blockIdx.x / nbc) << 5;
  int tx = threadIdx.x & 31, ty = threadIdx.x >> 5;
  #pragma unroll
  for (int rr = 0; rr < 32; rr += 8)
    t[ty + rr][tx] = in[(size_t)(r0 + ty + rr) * C + c0 + tx];
  __syncthreads();
  #pragma unroll
  for (int rr = 0; rr < 32; rr += 8)
    out[(size_t)(c0 + ty + rr) * R + r0 + tx] = (f16)t[tx][ty + rr];
}

// Wih rows permuted into c'-layout + scaled.
// c' = w*96 + l15*6 + s ; s -> g=s>>1, jj=s&1 ; orig row = g*256 + w*32 + jj*16 + l15
__global__ void cvt_wih_g(const float* __restrict__ Wih, f16* __restrict__ out) {
  const int cp = blockIdx.x;           // 0..767
  const int w = cp / 96, r = cp % 96, l15 = r / 6, s = r % 6;
  const int g = s >> 1, jj = s & 1;
  const int orig = g * 256 + w * 32 + jj * 16 + l15;
  const float sc = (g < 2) ? S_RZ : S_N;
  const float* src = Wih + (size_t)orig * 512;
  f16* dst = out + (size_t)cp * 512;
  for (int k = threadIdx.x; k < 512; k += 256) dst[k] = (f16)(sc * src[k]);
}
// Whh rows permuted into c''-layout + scaled.  c'' = w*96 + s*16 + l15
__global__ void cvt_whh_g(const float* __restrict__ Whh, f16* __restrict__ out) {
  const int cpp = blockIdx.x;          // 0..767
  const int w = cpp / 96, r = cpp % 96, s = r / 16, l15 = r % 16;
  const int g = s >> 1, jj = s & 1;
  const int orig = g * 256 + w * 32 + jj * 16 + l15;
  const float sc = (g < 2) ? S_RZ : S_N;
  const float* src = Whh + (size_t)orig * 256;
  f16* dst = out + (size_t)cpp * 256;
  dst[threadIdx.x] = (f16)(sc * src[threadIdx.x]);
}
__global__ void cvt_bias_g(const float* __restrict__ bih, const float* __restrict__ bhh,
                           float* __restrict__ bias_g, float* __restrict__ bhh_ng) {
  const int i = threadIdx.x + blockIdx.x * 256;   // 0..767
  {
    const int w = i / 96, r = i % 96, l15 = r / 6, s = r % 6;
    const int g = s >> 1, jj = s & 1;
    const int orig = g * 256 + w * 32 + jj * 16 + l15;
    const float sc = (g < 2) ? S_RZ : S_N;
    bias_g[i] = sc * (bih[orig] + ((g < 2) ? bhh[orig] : 0.f));
  }
  {
    const int w = i / 96, r = i % 96, s = r / 16, l15 = r % 16;
    const int g = s >> 1, jj = s & 1;
    const int orig = g * 256 + w * 32 + jj * 16 + l15;
    bhh_ng[i] = (g == 2) ? S_N * bhh[orig] : 0.f;
  }
}
// hist f16 [t][b][256] -> out f32 [b][t][256] with length mask
__global__ void expand_out(const f16* __restrict__ hist, const int* __restrict__ clen,
                           float* __restrict__ out) {
  const int row = blockIdx.x;          // b*512+t
  const int b = row >> 9, t = row & 511;
  const float v = (t < clen[b]) ? (float)hist[(size_t)((t << 4) + b) * 256 + threadIdx.x] : 0.f;
  out[(size_t)row * 256 + threadIdx.x] = v;
}

// ---------------- MFMA f16 GEMM (128x128 tile, BK=32) ----------------
// A [M,K] f16 (lda), B [N,K] f16 (ldb) -> C[M,N]
// EPI 0: Cf = acc + bias[col] (f32)
// EPI 1: Ch = f16( Gin * sigmoid(acc + bias[col]) )
// EPI 3: Ch = f16(acc + bias[col]) scattered into xp48 [t][lane][4j][6s] layout
template <int EPI>
__global__ __launch_bounds__(256, 2) void gemm_nt(
    const f16* __restrict__ A, int lda,
    const f16* __restrict__ B, int ldb,
    const float* __restrict__ bias,
    float* __restrict__ Cf, f16* __restrict__ Ch, const f16* __restrict__ Gin,
    int M, int N, int K) {
  __shared__ f16 As[2][128 * 32];
  __shared__ f16 Bs[2][128 * 32];
  const int tiles_n = N >> 7;
  const int bm = (blockIdx.x / tiles_n) << 7;
  const int bn = (blockIdx.x % tiles_n) << 7;
  const int tid = threadIdx.x, wv = tid >> 6, lane = tid & 63;
  const int lr = lane & 15, lk = lane >> 4;
  const int wm = (wv >> 1) << 6, wn = (wv & 1) << 6;
  const int srow = lane >> 2;
  const int scol = (lane & 3) << 3;
  f32x4 acc[4][4] = {};

  auto stage = [&](int buf, int kt) {
    const int k0 = kt << 5;
    #pragma unroll
    for (int c = 0; c < 2; ++c) {
      const int row = ((wv * 2 + c) << 4) + srow;
      load_lds_16(A + (size_t)(bm + row) * lda + k0 + scol,
                  &As[buf][(wv * 2 + c) * 512]);
      load_lds_16(B + (size_t)(bn + row) * ldb + k0 + scol,
                  &Bs[buf][(wv * 2 + c) * 512]);
    }
  };

  const int NT = K >> 5;
  stage(0, 0);
  for (int kt = 0; kt < NT; ++kt) {
    const int buf = kt & 1;
    __syncthreads();
    if (kt + 1 < NT) stage(buf ^ 1, kt + 1);
    f16x8 af[4], bf[4];
    #pragma unroll
    for (int i = 0; i < 4; ++i)
      af[i] = *(const f16x8*)&As[buf][(wm + i * 16 + lr) * 32 + lk * 8];
    #pragma unroll
    for (int i = 0; i < 4; ++i)
      bf[i] = *(const f16x8*)&Bs[buf][(wn + i * 16 + lr) * 32 + lk * 8];
    #pragma unroll
    for (int mi = 0; mi < 4; ++mi)
      #pragma unroll
      for (int ni = 0; ni < 4; ++ni)
        acc[mi][ni] = __builtin_amdgcn_mfma_f32_16x16x32_f16(af[mi], bf[ni], acc[mi][ni], 0, 0, 0);
    __syncthreads();
  }

  const int crow0 = bm + wm + lk * 4;
  const int ccol0 = bn + wn + lr;
  #pragma unroll
  for (int mi = 0; mi < 4; ++mi) {
    #pragma unroll
    for (int ni = 0; ni < 4; ++ni) {
      const int col = ccol0 + ni * 16;
      const float bv = bias[col];
      #pragma unroll
      for (int j = 0; j < 4; ++j) {
        const int row = crow0 + mi * 16 + j;
        const float v = acc[mi][ni][j] + bv;
        if constexpr (EPI == 0) {
          Cf[(size_t)row * N + col] = v;
        } else if constexpr (EPI == 1) {
          const float rin = (float)Gin[(size_t)row * N + col];
          Ch[(size_t)row * N + col] = (f16)(rin * sigm(v));
        } else {
          // scatter into xp48: t=row&511, b=row>>9; slot = wv*64 + (b>>2)*16 + l15
          const int tt = row & 511, bb = row >> 9;
          const int wvv = col / 96, rr = col % 96;
          const int l15v = rr / 6, sv = rr % 6;
          Ch[(size_t)tt * 12288 + (wvv * 64 + (bb >> 2) * 16 + l15v) * 24 + (bb & 3) * 6 + sv] = (f16)v;
        }
      }
    }
  }
}

// ---------------- fused additive attention ----------------
__global__ __launch_bounds__(256) void attn_kernel(
    const float* __restrict__ cd, const float* __restrict__ qd,
    const float* __restrict__ qrep, const float* __restrict__ Ws,
    const float* __restrict__ bsp, const float* __restrict__ qmask,
    f16* __restrict__ rnn_h) {
  const int b = blockIdx.x >> 4;
  const int pc = blockIdx.x & 15;
  __shared__ f16 qd_s[64][264];
  __shared__ float ws_s[256];
  __shared__ float cd_s[256];
  __shared__ float sc_s[64];
  __shared__ float msk[64];
  const int tid = threadIdx.x;
  const float* qdb = qd + (size_t)b * 64 * 256;
  for (int i = tid; i < 64 * 256; i += 256) qd_s[i >> 8][i & 255] = (f16)qdb[i];
  ws_s[tid] = Ws[tid];
  if (tid < 64) msk[tid] = qmask[b * 64 + tid];
  __syncthreads();
  const float bsv = bsp[0];
  const float* qr = qrep + (size_t)b * 64 * 256;
  const int q = tid >> 2, l4 = tid & 3;
  for (int pi = 0; pi < 32; ++pi) {
    const int p = (pc << 5) + pi;
    cd_s[tid] = cd[((size_t)b * 512 + p) * 256 + tid];
    __syncthreads();
    float s = 0.f;
    #pragma unroll 2
    for (int jj = 0; jj < 16; ++jj) {
      const int h0 = (l4 << 2) + (jj << 4);
      #pragma unroll
      for (int e = 0; e < 4; ++e) {
        const int hh = h0 + e;
        s += ws_s[hh] * tanhfast(cd_s[hh] + (float)qd_s[q][hh]);
      }
    }
    s += __shfl_xor(s, 1);
    s += __shfl_xor(s, 2);
    if (l4 == 0) sc_s[q] = (msk[q] > 0.f) ? (s + bsv) : -1e30f;
    __syncthreads();
    if (tid < 64) {
      float v = sc_s[tid], m = v;
      #pragma unroll
      for (int o = 32; o; o >>= 1) m = fmaxf(m, __shfl_xor(m, o));
      const float e = __expf(v - m);
      float su = e;
      #pragma unroll
      for (int o = 32; o; o >>= 1) su += __shfl_xor(su, o);
      sc_s[tid] = e / su;
    }
    __syncthreads();
    float a = 0.f;
    #pragma unroll 8
    for (int q2 = 0; q2 < 64; ++q2) a = fmaf(sc_s[q2], qr[q2 * 256 + tid], a);
    rnn_h[(((size_t)b * 512 + p) << 9) + 256 + tid] = (f16)a;
  }
}

// ---------------- GRU: single block, MFMA recurrence ----------------
// M=16 batches, N=768 (8 waves x 6 subtiles of 16), K=256, Whh resident in VGPRs.
// xp48: [512 t][512 lane][4 j][6 s] f16 (48B/lane/step) -> dwordx3 at imm offsets.
// h: double-buffered LDS [16][256] f16, XOR-swizzled byte ^= (b&7)<<4.
// output: hist f16 [t][b][256] via advancing base + imm offsets.
__global__ __launch_bounds__(512, 2) void gru_mfma(
    const f16* __restrict__ xp48, const f16* __restrict__ Whh_g,
    const float* __restrict__ bhh_ng, f16* __restrict__ hist) {
  const int tid = threadIdx.x;
  const int wv = tid >> 6, l = tid & 63, l15 = l & 15, lh = l >> 4;
  __shared__ char hs[2][16 * 512];
  for (int i = tid; i < 2048; i += 512) {
    ((float*)hs[0])[i] = 0.f;
    ((float*)hs[1])[i] = 0.f;
  }

  // Whh B-fragments: row c'' = wv*96 + s*16 + l15, k = kt*32 + lh*8
  f16x8 wb[6][8];
  #pragma unroll
  for (int s = 0; s < 6; ++s)
    #pragma unroll
    for (int kt = 0; kt < 8; ++kt)
      wb[s][kt] = *(const f16x8*)(Whh_g + (size_t)(wv * 96 + s * 16 + l15) * 256 + kt * 32 + lh * 8);

  const float bhn0 = bhh_ng[wv * 96 + 64 + l15];
  const float bhn1 = bhh_ng[wv * 96 + 80 + l15];

  unsigned h2[4];
  #pragma unroll
  for (int j = 0; j < 4; ++j) h2[j] = 0u;

  const char* xb = (const char*)xp48 + (wv * 64 + l) * 48;
  f16* ho = hist + (lh * 4) * 256 + wv * 32 + l15;
  uint3 xq[4];
  #pragma unroll
  for (int j = 0; j < 4; ++j) xq[j] = *(const uint3*)(xb + j * 12);
  xb += 24576;
  __syncthreads();

  for (int t = 0; t < 512; ++t) {
    const int cur = t & 1;
    f32x4 acc[6];
    unsigned xnp[4];
    #pragma unroll
    for (int j = 0; j < 4; ++j) {
      f16x2 rr = __builtin_bit_cast(f16x2, xq[j].x);
      f16x2 zz = __builtin_bit_cast(f16x2, xq[j].y);
      acc[0][j] = (float)rr.x; acc[1][j] = (float)rr.y;
      acc[2][j] = (float)zz.x; acc[3][j] = (float)zz.y;
      xnp[j] = xq[j].z;
      acc[4][j] = bhn0;        acc[5][j] = bhn1;
    }
    if (t < 511) {                      // prefetch next step (hides under MFMA)
      #pragma unroll
      for (int j = 0; j < 4; ++j) xq[j] = *(const uint3*)(xb + j * 12);
      xb += 24576;
    }
    const char* hb = hs[cur];
    #pragma unroll
    for (int kt = 0; kt < 8; ++kt) {
      const int off = (l15 * 512 + kt * 64 + lh * 16) ^ ((l15 & 7) << 4);
      f16x8 a = *(const f16x8*)(hb + off);
      #pragma unroll
      for (int s = 0; s < 6; ++s)
        acc[s] = __builtin_amdgcn_mfma_f32_16x16x32_f16(a, wb[s][kt], acc[s], 0, 0, 0);
    }
    char* hw = hs[cur ^ 1];
    #pragma unroll
    for (int j = 0; j < 4; ++j) {
      const int b = lh * 4 + j;
      const f16x2 hold = __builtin_bit_cast(f16x2, h2[j]);
      const f16x2 xn = __builtin_bit_cast(f16x2, xnp[j]);
      float hn0, hn1;
      {
        const float r = __builtin_amdgcn_rcpf(1.f + __builtin_amdgcn_exp2f(acc[0][j]));
        const float z = __builtin_amdgcn_rcpf(1.f + __builtin_amdgcn_exp2f(acc[2][j]));
        const float yy = fmaf(r, acc[4][j], (float)xn.x);
        const float n = fmaf(-2.f, __builtin_amdgcn_rcpf(1.f + __builtin_amdgcn_exp2f(yy)), 1.f);
        hn0 = fmaf(z, (float)hold.x - n, n);
      }
      {
        const float r = __builtin_amdgcn_rcpf(1.f + __builtin_amdgcn_exp2f(acc[1][j]));
        const float z = __builtin_amdgcn_rcpf(1.f + __builtin_amdgcn_exp2f(acc[3][j]));
        const float yy = fmaf(r, acc[5][j], (float)xn.y);
        const float n = fmaf(-2.f, __builtin_amdgcn_rcpf(1.f + __builtin_amdgcn_exp2f(yy)), 1.f);
        hn1 = fmaf(z, (float)hold.y - n, n);
      }
      const f16 h0h = (f16)hn0, h1h = (f16)hn1;
      ho[j * 256]      = h0h;
      ho[j * 256 + 16] = h1h;
      h2[j] = __builtin_bit_cast(unsigned, (f16x2){h0h, h1h});
      *(f16*)(hw + ((b * 512 + (wv * 32 + l15) * 2) ^ ((b & 7) << 4))) = h0h;
      *(f16*)(hw + ((b * 512 + (wv * 32 + 16 + l15) * 2) ^ ((b & 7) << 4))) = h1h;
    }
    ho += 4096;
    __syncthreads();
  }
}

// ---------------- launch ----------------
extern "C" void kernel_launch(void* const* d_in, const int* in_sizes, int n_in,
                              void* d_out, int out_size, void* d_ws, size_t ws_size,
                              hipStream_t stream) {
  const float* ctx   = (const float*)d_in[0];
  const float* qrep  = (const float*)d_in[1];
  const int*   clen  = (const int*)d_in[2];
  const float* qmask = (const float*)d_in[3];
  const float* Wc    = (const float*)d_in[4];
  const float* bc    = (const float*)d_in[5];
  const float* Wq    = (const float*)d_in[6];
  const float* bq    = (const float*)d_in[7];
  const float* Ws    = (const float*)d_in[8];
  const float* bs    = (const float*)d_in[9];
  const float* Wg    = (const float*)d_in[10];
  const float* bg    = (const float*)d_in[11];
  const float* Wih   = (const float*)d_in[12];
  const float* Whh   = (const float*)d_in[13];
  const float* bih   = (const float*)d_in[14];
  const float* bhh   = (const float*)d_in[15];
  float* out = (float*)d_out;

  char* w = (char*)d_ws;
  auto alloc = [&](size_t bytes) -> void* {
    void* p = (void*)w;
    w += (bytes + 255) & ~(size_t)255;
    return p;
  };
  const int M = kB * kLC;                 // 8192
  // keep peak ws identical to the passing round-2 layout (~40 MB):
  // hist (4 MB) aliases cd (8 MB) — cd is dead after attn_kernel.
  float* cd     = (float*)alloc((size_t)M * 256 * 4);
  float* qd     = (float*)alloc((size_t)1024 * 256 * 4);
  f16* rnn_h    = (f16*)alloc((size_t)M * 512 * 2);
  f16* q_h      = (f16*)alloc((size_t)1024 * 256 * 2);
  f16* g_h      = (f16*)alloc((size_t)M * 512 * 2);
  f16* xp48     = (f16*)alloc((size_t)512 * 12288 * 2);
  f16* Wct_h    = (f16*)alloc((size_t)256 * 256 * 2);
  f16* Wqt_h    = (f16*)alloc((size_t)256 * 256 * 2);
  f16* Wgt_h    = (f16*)alloc((size_t)512 * 512 * 2);
  f16* Wih_g    = (f16*)alloc((size_t)768 * 512 * 2);
  f16* Whh_g    = (f16*)alloc((size_t)768 * 256 * 2);
  float* bias_g = (float*)alloc(768 * 4);
  float* bhh_ng = (float*)alloc(768 * 4);
  f16* hist     = (f16*)cd;               // alias (4 MB <= 8 MB, disjoint lifetime)

  // conversions
  cvt_ctx   <<<M, 256, 0, stream>>>(ctx, rnn_h);
  cvt_flat  <<<1024, 256, 0, stream>>>(qrep, q_h, 1024 * 256);
  cvt_tr    <<<64, 256, 0, stream>>>(Wc, Wct_h, 256, 256);
  cvt_tr    <<<64, 256, 0, stream>>>(Wq, Wqt_h, 256, 256);
  cvt_tr    <<<256, 256, 0, stream>>>(Wg, Wgt_h, 512, 512);
  cvt_wih_g <<<768, 256, 0, stream>>>(Wih, Wih_g);
  cvt_whh_g <<<768, 256, 0, stream>>>(Whh, Whh_g);
  cvt_bias_g<<<3, 256, 0, stream>>>(bih, bhh, bias_g, bhh_ng);

  // cd = ctx @ Wc + bc ; qd = q @ Wq + bq
  gemm_nt<0><<<(M / 128) * (256 / 128), 256, 0, stream>>>(
      rnn_h, 512, Wct_h, 256, bc, cd, nullptr, nullptr, M, 256, 256);
  gemm_nt<0><<<(1024 / 128) * (256 / 128), 256, 0, stream>>>(
      q_h, 256, Wqt_h, 256, bq, qd, nullptr, nullptr, 1024, 256, 256);

  // attention -> rnn_h[:, 256:512]
  attn_kernel<<<256, 256, 0, stream>>>(cd, qd, qrep, Ws, bs, qmask, rnn_h);

  // g = rnn_in * sigmoid(rnn_in @ Wg + bg)
  gemm_nt<1><<<(M / 128) * (512 / 128), 256, 0, stream>>>(
      rnn_h, 512, Wgt_h, 512, bg, nullptr, g_h, rnn_h, M, 512, 512);

  // xp48 = f16( g @ Wih_g.T + bias_g )  scattered into [t][lane][48B] layout
  gemm_nt<3><<<(M / 128) * (768 / 128), 256, 0, stream>>>(
      g_h, 512, Wih_g, 512, bias_g, nullptr, xp48, nullptr, M, 768, 512);

  // GRU recurrence (single block, MFMA, weights in VGPRs)
  gru_mfma<<<1, 512, 0, stream>>>(xp48, Whh_g, bhh_ng, hist);

  // hist -> out (f32, masked)
  expand_out<<<M, 256, 0, stream>>>(hist, clen, out);
}

// Round 5
// 1142.464 us; speedup vs baseline: 1.3096x; 1.2468x over previous
//
#include <hip/hip_runtime.h>
#include <hip/hip_fp16.h>

typedef _Float16 f16;
typedef _Float16 f16x8 __attribute__((ext_vector_type(8)));
typedef _Float16 f16x2 __attribute__((ext_vector_type(2)));
typedef float f32x4 __attribute__((ext_vector_type(4)));

static constexpr int kB  = 16;
static constexpr int kLC = 512;

// gate scales folded into weights: sigm(x)=1/(1+exp2(-x*log2e)); tanh(y)=1-2/(1+exp2(y*2log2e))
#define S_RZ (-1.4426950408889634f)
#define S_N  ( 2.8853900817779268f)

// ---------------- helpers ----------------
__device__ __forceinline__ float sigm(float x) { return 1.f / (1.f + __expf(-x)); }
__device__ __forceinline__ float tanhfast(float x) {
  float xc = fminf(fmaxf(x, -15.f), 15.f);
  float e = __expf(2.f * xc);
  return (e - 1.f) / (e + 1.f);
}
__device__ __forceinline__ void load_lds_16(const void* g, void* l) {
  __builtin_amdgcn_global_load_lds(
      (const __attribute__((address_space(1))) void*)g,
      (__attribute__((address_space(3))) void*)(unsigned)(unsigned long long)l,
      16, 0, 0);
}

// ---------------- conversion kernels ----------------
__global__ void cvt_flat(const float* __restrict__ in, f16* __restrict__ out, int n) {
  int i = blockIdx.x * 256 + threadIdx.x;
  if (i < n) out[i] = (f16)in[i];
}
__global__ void cvt_ctx(const float* __restrict__ in, f16* __restrict__ out) {
  int i = blockIdx.x * 256 + threadIdx.x;
  int r = i >> 8, c = i & 255;
  out[r * 512 + c] = (f16)in[i];
}
__global__ void cvt_tr(const float* __restrict__ in, f16* __restrict__ out, int R, int C) {
  __shared__ float t[32][33];
  int nbc = C >> 5;
  int c0 = (blockIdx.x % nbc) << 5;
  int r0 = (blockIdx.x / nbc) << 5;
  int tx = threadIdx.x & 31, ty = threadIdx.x >> 5;
  #pragma unroll
  for (int rr = 0; rr < 32; rr += 8)
    t[ty + rr][tx] = in[(size_t)(r0 + ty + rr) * C + c0 + tx];
  __syncthreads();
  #pragma unroll
  for (int rr = 0; rr < 32; rr += 8)
    out[(size_t)(c0 + ty + rr) * R + r0 + tx] = (f16)t[tx][ty + rr];
}

// Wih rows permuted into c'-layout + scaled.
// c' = w*96 + l15*6 + s ; s -> g=s>>1, jj=s&1 ; orig row = g*256 + w*32 + jj*16 + l15
__global__ void cvt_wih_g(const float* __restrict__ Wih, f16* __restrict__ out) {
  const int cp = blockIdx.x;           // 0..767
  const int w = cp / 96, r = cp % 96, l15 = r / 6, s = r % 6;
  const int g = s >> 1, jj = s & 1;
  const int orig = g * 256 + w * 32 + jj * 16 + l15;
  const float sc = (g < 2) ? S_RZ : S_N;
  const float* src = Wih + (size_t)orig * 512;
  f16* dst = out + (size_t)cp * 512;
  for (int k = threadIdx.x; k < 512; k += 256) dst[k] = (f16)(sc * src[k]);
}
// Whh rows permuted into c''-layout + scaled.  c'' = w*96 + s*16 + l15
__global__ void cvt_whh_g(const float* __restrict__ Whh, f16* __restrict__ out) {
  const int cpp = blockIdx.x;          // 0..767
  const int w = cpp / 96, r = cpp % 96, s = r / 16, l15 = r % 16;
  const int g = s >> 1, jj = s & 1;
  const int orig = g * 256 + w * 32 + jj * 16 + l15;
  const float sc = (g < 2) ? S_RZ : S_N;
  const float* src = Whh + (size_t)orig * 256;
  f16* dst = out + (size_t)cpp * 256;
  dst[threadIdx.x] = (f16)(sc * src[threadIdx.x]);
}
__global__ void cvt_bias_g(const float* __restrict__ bih, const float* __restrict__ bhh,
                           float* __restrict__ bias_g, float* __restrict__ bhh_ng) {
  const int i = threadIdx.x + blockIdx.x * 256;   // 0..767
  {
    const int w = i / 96, r = i % 96, l15 = r / 6, s = r % 6;
    const int g = s >> 1, jj = s & 1;
    const int orig = g * 256 + w * 32 + jj * 16 + l15;
    const float sc = (g < 2) ? S_RZ : S_N;
    bias_g[i] = sc * (bih[orig] + ((g < 2) ? bhh[orig] : 0.f));
  }
  {
    const int w = i / 96, r = i % 96, s = r / 16, l15 = r % 16;
    const int g = s >> 1, jj = s & 1;
    const int orig = g * 256 + w * 32 + jj * 16 + l15;
    bhh_ng[i] = (g == 2) ? S_N * bhh[orig] : 0.f;
  }
}
// hist2 u32 [t][b][wv][16] (u32 = cols (wv*32+l15, wv*32+16+l15)) -> out f32 [b][t][256], masked
__global__ void expand_out(const unsigned* __restrict__ hist2, const int* __restrict__ clen,
                           float* __restrict__ out) {
  const int row = blockIdx.x;          // b*512+t
  const int b = row >> 9, t = row & 511;
  const int c = threadIdx.x;
  float v = 0.f;
  if (t < clen[b]) {
    const unsigned u = hist2[(size_t)(t * 16 + b) * 128 + (c >> 5) * 16 + (c & 15)];
    const f16x2 p = __builtin_bit_cast(f16x2, u);
    v = ((c & 31) < 16) ? (float)p.x : (float)p.y;
  }
  out[(size_t)row * 256 + c] = v;
}

// ---------------- MFMA f16 GEMM (128x128 tile, BK=32) ----------------
// A [M,K] f16 (lda), B [N,K] f16 (ldb) -> C[M,N]
// EPI 0: Cf = acc + bias[col] (f32)
// EPI 1: Ch = f16( Gin * sigmoid(acc + bias[col]) )
// EPI 3: Ch = f16(acc + bias[col]) scattered into xp48 [t][lane][4j][6s] layout
template <int EPI>
__global__ __launch_bounds__(256, 2) void gemm_nt(
    const f16* __restrict__ A, int lda,
    const f16* __restrict__ B, int ldb,
    const float* __restrict__ bias,
    float* __restrict__ Cf, f16* __restrict__ Ch, const f16* __restrict__ Gin,
    int M, int N, int K) {
  __shared__ f16 As[2][128 * 32];
  __shared__ f16 Bs[2][128 * 32];
  const int tiles_n = N >> 7;
  const int bm = (blockIdx.x / tiles_n) << 7;
  const int bn = (blockIdx.x % tiles_n) << 7;
  const int tid = threadIdx.x, wv = tid >> 6, lane = tid & 63;
  const int lr = lane & 15, lk = lane >> 4;
  const int wm = (wv >> 1) << 6, wn = (wv & 1) << 6;
  const int srow = lane >> 2;
  const int scol = (lane & 3) << 3;
  f32x4 acc[4][4] = {};

  auto stage = [&](int buf, int kt) {
    const int k0 = kt << 5;
    #pragma unroll
    for (int c = 0; c < 2; ++c) {
      const int row = ((wv * 2 + c) << 4) + srow;
      load_lds_16(A + (size_t)(bm + row) * lda + k0 + scol,
                  &As[buf][(wv * 2 + c) * 512]);
      load_lds_16(B + (size_t)(bn + row) * ldb + k0 + scol,
                  &Bs[buf][(wv * 2 + c) * 512]);
    }
  };

  const int NT = K >> 5;
  stage(0, 0);
  for (int kt = 0; kt < NT; ++kt) {
    const int buf = kt & 1;
    __syncthreads();
    if (kt + 1 < NT) stage(buf ^ 1, kt + 1);
    f16x8 af[4], bf[4];
    #pragma unroll
    for (int i = 0; i < 4; ++i)
      af[i] = *(const f16x8*)&As[buf][(wm + i * 16 + lr) * 32 + lk * 8];
    #pragma unroll
    for (int i = 0; i < 4; ++i)
      bf[i] = *(const f16x8*)&Bs[buf][(wn + i * 16 + lr) * 32 + lk * 8];
    #pragma unroll
    for (int mi = 0; mi < 4; ++mi)
      #pragma unroll
      for (int ni = 0; ni < 4; ++ni)
        acc[mi][ni] = __builtin_amdgcn_mfma_f32_16x16x32_f16(af[mi], bf[ni], acc[mi][ni], 0, 0, 0);
    __syncthreads();
  }

  const int crow0 = bm + wm + lk * 4;
  const int ccol0 = bn + wn + lr;
  #pragma unroll
  for (int mi = 0; mi < 4; ++mi) {
    #pragma unroll
    for (int ni = 0; ni < 4; ++ni) {
      const int col = ccol0 + ni * 16;
      const float bv = bias[col];
      #pragma unroll
      for (int j = 0; j < 4; ++j) {
        const int row = crow0 + mi * 16 + j;
        const float v = acc[mi][ni][j] + bv;
        if constexpr (EPI == 0) {
          Cf[(size_t)row * N + col] = v;
        } else if constexpr (EPI == 1) {
          const float rin = (float)Gin[(size_t)row * N + col];
          Ch[(size_t)row * N + col] = (f16)(rin * sigm(v));
        } else {
          // scatter into xp48: t=row&511, b=row>>9; slot = wv*64 + (b>>2)*16 + l15
          const int tt = row & 511, bb = row >> 9;
          const int wvv = col / 96, rr = col % 96;
          const int l15v = rr / 6, sv = rr % 6;
          Ch[(size_t)tt * 12288 + (wvv * 64 + (bb >> 2) * 16 + l15v) * 24 + (bb & 3) * 6 + sv] = (f16)v;
        }
      }
    }
  }
}

// ---------------- fused additive attention ----------------
__global__ __launch_bounds__(256) void attn_kernel(
    const float* __restrict__ cd, const float* __restrict__ qd,
    const float* __restrict__ qrep, const float* __restrict__ Ws,
    const float* __restrict__ bsp, const float* __restrict__ qmask,
    f16* __restrict__ rnn_h) {
  const int b = blockIdx.x >> 4;
  const int pc = blockIdx.x & 15;
  __shared__ f16 qd_s[64][264];
  __shared__ float ws_s[256];
  __shared__ float cd_s[256];
  __shared__ float sc_s[64];
  __shared__ float msk[64];
  const int tid = threadIdx.x;
  const float* qdb = qd + (size_t)b * 64 * 256;
  for (int i = tid; i < 64 * 256; i += 256) qd_s[i >> 8][i & 255] = (f16)qdb[i];
  ws_s[tid] = Ws[tid];
  if (tid < 64) msk[tid] = qmask[b * 64 + tid];
  __syncthreads();
  const float bsv = bsp[0];
  const float* qr = qrep + (size_t)b * 64 * 256;
  const int q = tid >> 2, l4 = tid & 3;
  for (int pi = 0; pi < 32; ++pi) {
    const int p = (pc << 5) + pi;
    cd_s[tid] = cd[((size_t)b * 512 + p) * 256 + tid];
    __syncthreads();
    float s = 0.f;
    #pragma unroll 2
    for (int jj = 0; jj < 16; ++jj) {
      const int h0 = (l4 << 2) + (jj << 4);
      #pragma unroll
      for (int e = 0; e < 4; ++e) {
        const int hh = h0 + e;
        s += ws_s[hh] * tanhfast(cd_s[hh] + (float)qd_s[q][hh]);
      }
    }
    s += __shfl_xor(s, 1);
    s += __shfl_xor(s, 2);
    if (l4 == 0) sc_s[q] = (msk[q] > 0.f) ? (s + bsv) : -1e30f;
    __syncthreads();
    if (tid < 64) {
      float v = sc_s[tid], m = v;
      #pragma unroll
      for (int o = 32; o; o >>= 1) m = fmaxf(m, __shfl_xor(m, o));
      const float e = __expf(v - m);
      float su = e;
      #pragma unroll
      for (int o = 32; o; o >>= 1) su += __shfl_xor(su, o);
      sc_s[tid] = e / su;
    }
    __syncthreads();
    float a = 0.f;
    #pragma unroll 8
    for (int q2 = 0; q2 < 64; ++q2) a = fmaf(sc_s[q2], qr[q2 * 256 + tid], a);
    rnn_h[(((size_t)b * 512 + p) << 9) + 256 + tid] = (f16)a;
  }
}

// ---------------- GRU: single block, MFMA recurrence ----------------
// M=16 batches, N=768 (8 waves x 6 subtiles of 16), K=256, Whh resident in VGPRs.
// xp48: [512 t][512 lane][4 j][6 s] f16 (48B/lane/step) -> dwordx3 at saddr+voffset.
// h: double-buffered LDS [16][256] f16, XOR-swizzled byte ^= (b&7)<<4.
// output: hist2 u32 [t][b][wv][16], one packed store per (lane,j).
// amdgpu_waves_per_eu(2): min 2 waves/EU -> VGPR cap 256 (need ~250 for wb-resident).
__global__ __launch_bounds__(512) __attribute__((amdgpu_waves_per_eu(2)))
void gru_mfma(
    const f16* __restrict__ xp48, const f16* __restrict__ Whh_g,
    const float* __restrict__ bhh_ng, unsigned* __restrict__ hist2) {
  const int tid = threadIdx.x;
  const int wv = tid >> 6, l = tid & 63, l15 = l & 15, lh = l >> 4;
  __shared__ char hs[2][16 * 512];
  for (int i = tid; i < 2048; i += 512) {
    ((float*)hs[0])[i] = 0.f;
    ((float*)hs[1])[i] = 0.f;
  }

  // Whh B-fragments: row c'' = wv*96 + s*16 + l15, k = kt*32 + lh*8
  f16x8 wb[6][8];
  #pragma unroll
  for (int s = 0; s < 6; ++s)
    #pragma unroll
    for (int kt = 0; kt < 8; ++kt)
      wb[s][kt] = *(const f16x8*)(Whh_g + (size_t)(wv * 96 + s * 16 + l15) * 256 + kt * 32 + lh * 8);

  const float bhn0 = bhh_ng[wv * 96 + 64 + l15];
  const float bhn1 = bhh_ng[wv * 96 + 80 + l15];

  unsigned h2[4];
  #pragma unroll
  for (int j = 0; j < 4; ++j) h2[j] = 0u;

  const char* xbase = (const char*)xp48;
  char* hbase = (char*)hist2;
  unsigned xoff = (wv * 64 + l) * 48;                       // advances 24576 B/step
  unsigned hoff = lh * 2048 + wv * 64 + l15 * 4;            // advances 8192 B/step
  uint3 xq[4];
  #pragma unroll
  for (int j = 0; j < 4; ++j) xq[j] = *(const uint3*)(xbase + xoff + j * 12);
  xoff += 24576;
  __syncthreads();

  for (int t = 0; t < 512; ++t) {
    const int cur = t & 1;
    f32x4 acc[6];
    unsigned xnp[4];
    #pragma unroll
    for (int j = 0; j < 4; ++j) {
      f16x2 rr = __builtin_bit_cast(f16x2, xq[j].x);
      f16x2 zz = __builtin_bit_cast(f16x2, xq[j].y);
      acc[0][j] = (float)rr.x; acc[1][j] = (float)rr.y;
      acc[2][j] = (float)zz.x; acc[3][j] = (float)zz.y;
      xnp[j] = xq[j].z;
      acc[4][j] = bhn0;        acc[5][j] = bhn1;
    }
    if (t < 511) {                      // prefetch next step (hides under MFMA)
      #pragma unroll
      for (int j = 0; j < 4; ++j) xq[j] = *(const uint3*)(xbase + xoff + j * 12);
      xoff += 24576;
    }
    const char* hb = hs[cur];
    #pragma unroll
    for (int kt = 0; kt < 8; ++kt) {
      const int off = (l15 * 512 + kt * 64 + lh * 16) ^ ((l15 & 7) << 4);
      f16x8 a = *(const f16x8*)(hb + off);
      #pragma unroll
      for (int s = 0; s < 6; ++s)
        acc[s] = __builtin_amdgcn_mfma_f32_16x16x32_f16(a, wb[s][kt], acc[s], 0, 0, 0);
    }
    char* hw = hs[cur ^ 1];
    #pragma unroll
    for (int j = 0; j < 4; ++j) {
      const int b = lh * 4 + j;
      const f16x2 hold = __builtin_bit_cast(f16x2, h2[j]);
      const f16x2 xn = __builtin_bit_cast(f16x2, xnp[j]);
      float hn0, hn1;
      {
        const float r = __builtin_amdgcn_rcpf(1.f + __builtin_amdgcn_exp2f(acc[0][j]));
        const float z = __builtin_amdgcn_rcpf(1.f + __builtin_amdgcn_exp2f(acc[2][j]));
        const float yy = fmaf(r, acc[4][j], (float)xn.x);
        const float n = fmaf(-2.f, __builtin_amdgcn_rcpf(1.f + __builtin_amdgcn_exp2f(yy)), 1.f);
        hn0 = fmaf(z, (float)hold.x - n, n);
      }
      {
        const float r = __builtin_amdgcn_rcpf(1.f + __builtin_amdgcn_exp2f(acc[1][j]));
        const float z = __builtin_amdgcn_rcpf(1.f + __builtin_amdgcn_exp2f(acc[3][j]));
        const float yy = fmaf(r, acc[5][j], (float)xn.y);
        const float n = fmaf(-2.f, __builtin_amdgcn_rcpf(1.f + __builtin_amdgcn_exp2f(yy)), 1.f);
        hn1 = fmaf(z, (float)hold.y - n, n);
      }
      const f16 h0h = (f16)hn0, h1h = (f16)hn1;
      h2[j] = __builtin_bit_cast(unsigned, (f16x2){h0h, h1h});
      *(unsigned*)(hbase + hoff + j * 512) = h2[j];
      *(f16*)(hw + ((b * 512 + (wv * 32 + l15) * 2) ^ ((b & 7) << 4))) = h0h;
      *(f16*)(hw + ((b * 512 + (wv * 32 + 16 + l15) * 2) ^ ((b & 7) << 4))) = h1h;
    }
    hoff += 8192;
    __syncthreads();
  }
}

// ---------------- launch ----------------
extern "C" void kernel_launch(void* const* d_in, const int* in_sizes, int n_in,
                              void* d_out, int out_size, void* d_ws, size_t ws_size,
                              hipStream_t stream) {
  const float* ctx   = (const float*)d_in[0];
  const float* qrep  = (const float*)d_in[1];
  const int*   clen  = (const int*)d_in[2];
  const float* qmask = (const float*)d_in[3];
  const float* Wc    = (const float*)d_in[4];
  const float* bc    = (const float*)d_in[5];
  const float* Wq    = (const float*)d_in[6];
  const float* bq    = (const float*)d_in[7];
  const float* Ws    = (const float*)d_in[8];
  const float* bs    = (const float*)d_in[9];
  const float* Wg    = (const float*)d_in[10];
  const float* bg    = (const float*)d_in[11];
  const float* Wih   = (const float*)d_in[12];
  const float* Whh   = (const float*)d_in[13];
  const float* bih   = (const float*)d_in[14];
  const float* bhh   = (const float*)d_in[15];
  float* out = (float*)d_out;

  char* w = (char*)d_ws;
  auto alloc = [&](size_t bytes) -> void* {
    void* p = (void*)w;
    w += (bytes + 255) & ~(size_t)255;
    return p;
  };
  const int M = kB * kLC;                 // 8192
  // hist2 (4 MB) aliases cd (8 MB) — cd is dead after attn_kernel.
  float* cd     = (float*)alloc((size_t)M * 256 * 4);
  float* qd     = (float*)alloc((size_t)1024 * 256 * 4);
  f16* rnn_h    = (f16*)alloc((size_t)M * 512 * 2);
  f16* q_h      = (f16*)alloc((size_t)1024 * 256 * 2);
  f16* g_h      = (f16*)alloc((size_t)M * 512 * 2);
  f16* xp48     = (f16*)alloc((size_t)512 * 12288 * 2);
  f16* Wct_h    = (f16*)alloc((size_t)256 * 256 * 2);
  f16* Wqt_h    = (f16*)alloc((size_t)256 * 256 * 2);
  f16* Wgt_h    = (f16*)alloc((size_t)512 * 512 * 2);
  f16* Wih_g    = (f16*)alloc((size_t)768 * 512 * 2);
  f16* Whh_g    = (f16*)alloc((size_t)768 * 256 * 2);
  float* bias_g = (float*)alloc(768 * 4);
  float* bhh_ng = (float*)alloc(768 * 4);
  unsigned* hist2 = (unsigned*)cd;        // alias (4 MB <= 8 MB, disjoint lifetime)

  // conversions
  cvt_ctx   <<<M, 256, 0, stream>>>(ctx, rnn_h);
  cvt_flat  <<<1024, 256, 0, stream>>>(qrep, q_h, 1024 * 256);
  cvt_tr    <<<64, 256, 0, stream>>>(Wc, Wct_h, 256, 256);
  cvt_tr    <<<64, 256, 0, stream>>>(Wq, Wqt_h, 256, 256);
  cvt_tr    <<<256, 256, 0, stream>>>(Wg, Wgt_h, 512, 512);
  cvt_wih_g <<<768, 256, 0, stream>>>(Wih, Wih_g);
  cvt_whh_g <<<768, 256, 0, stream>>>(Whh, Whh_g);
  cvt_bias_g<<<3, 256, 0, stream>>>(bih, bhh, bias_g, bhh_ng);

  // cd = ctx @ Wc + bc ; qd = q @ Wq + bq
  gemm_nt<0><<<(M / 128) * (256 / 128), 256, 0, stream>>>(
      rnn_h, 512, Wct_h, 256, bc, cd, nullptr, nullptr, M, 256, 256);
  gemm_nt<0><<<(1024 / 128) * (256 / 128), 256, 0, stream>>>(
      q_h, 256, Wqt_h, 256, bq, qd, nullptr, nullptr, 1024, 256, 256);

  // attention -> rnn_h[:, 256:512]
  attn_kernel<<<256, 256, 0, stream>>>(cd, qd, qrep, Ws, bs, qmask, rnn_h);

  // g = rnn_in * sigmoid(rnn_in @ Wg + bg)
  gemm_nt<1><<<(M / 128) * (512 / 128), 256, 0, stream>>>(
      rnn_h, 512, Wgt_h, 512, bg, nullptr, g_h, rnn_h, M, 512, 512);

  // xp48 = f16( g @ Wih_g.T + bias_g )  scattered into [t][lane][48B] layout
  gemm_nt<3><<<(M / 128) * (768 / 128), 256, 0, stream>>>(
      g_h, 512, Wih_g, 512, bias_g, nullptr, xp48, nullptr, M, 768, 512);

  // GRU recurrence (single block, MFMA, weights in VGPRs)
  gru_mfma<<<1, 512, 0, stream>>>(xp48, Whh_g, bhh_ng, hist2);

  // hist2 -> out (f32, masked)
  expand_out<<<M, 256, 0, stream>>>(hist2, clen, out);
}

// Round 7
// 971.958 us; speedup vs baseline: 1.5394x; 1.1754x over previous
//
#include <hip/hip_runtime.h>
#include <hip/hip_fp16.h>

typedef _Float16 f16;
typedef _Float16 f16x8 __attribute__((ext_vector_type(8)));
typedef _Float16 f16x2 __attribute__((ext_vector_type(2)));
typedef float f32x4 __attribute__((ext_vector_type(4)));

static constexpr int kB  = 16;
static constexpr int kLC = 512;

// gate scales folded into weights: sigm(x)=1/(1+exp2(-x*log2e)); tanh(y)=1-2/(1+exp2(y*2log2e))
#define S_RZ (-1.4426950408889634f)
#define S_N  ( 2.8853900817779268f)

// ---------------- helpers ----------------
__device__ __forceinline__ float sigm(float x) { return 1.f / (1.f + __expf(-x)); }
__device__ __forceinline__ float tanhfast(float x) {
  float xc = fminf(fmaxf(x, -15.f), 15.f);
  float e = __expf(2.f * xc);
  return (e - 1.f) / (e + 1.f);
}
__device__ __forceinline__ void load_lds_16(const void* g, void* l) {
  __builtin_amdgcn_global_load_lds(
      (const __attribute__((address_space(1))) void*)g,
      (__attribute__((address_space(3))) void*)(unsigned)(unsigned long long)l,
      16, 0, 0);
}

// ---------------- conversion kernels ----------------
__global__ void cvt_flat(const float* __restrict__ in, f16* __restrict__ out, int n) {
  int i = blockIdx.x * 256 + threadIdx.x;
  if (i < n) out[i] = (f16)in[i];
}
__global__ void cvt_ctx(const float* __restrict__ in, f16* __restrict__ out) {
  int i = blockIdx.x * 256 + threadIdx.x;
  int r = i >> 8, c = i & 255;
  out[r * 512 + c] = (f16)in[i];
}
__global__ void cvt_tr(const float* __restrict__ in, f16* __restrict__ out, int R, int C) {
  __shared__ float t[32][33];
  int nbc = C >> 5;
  int c0 = (blockIdx.x % nbc) << 5;
  int r0 = (blockIdx.x / nbc) << 5;
  int tx = threadIdx.x & 31, ty = threadIdx.x >> 5;
  #pragma unroll
  for (int rr = 0; rr < 32; rr += 8)
    t[ty + rr][tx] = in[(size_t)(r0 + ty + rr) * C + c0 + tx];
  __syncthreads();
  #pragma unroll
  for (int rr = 0; rr < 32; rr += 8)
    out[(size_t)(c0 + ty + rr) * R + r0 + tx] = (f16)t[tx][ty + rr];
}

// Wih rows permuted into c'-layout + scaled.
// c' = w*96 + l15*6 + s ; s -> g=s>>1, jj=s&1 ; orig row = g*256 + w*32 + jj*16 + l15
__global__ void cvt_wih_g(const float* __restrict__ Wih, f16* __restrict__ out) {
  const int cp = blockIdx.x;           // 0..767
  const int w = cp / 96, r = cp % 96, l15 = r / 6, s = r % 6;
  const int g = s >> 1, jj = s & 1;
  const int orig = g * 256 + w * 32 + jj * 16 + l15;
  const float sc = (g < 2) ? S_RZ : S_N;
  const float* src = Wih + (size_t)orig * 512;
  f16* dst = out + (size_t)cp * 512;
  for (int k = threadIdx.x; k < 512; k += 256) dst[k] = (f16)(sc * src[k]);
}
// Whh rows permuted into c''-layout + scaled.  c'' = w*96 + s*16 + l15
__global__ void cvt_whh_g(const float* __restrict__ Whh, f16* __restrict__ out) {
  const int cpp = blockIdx.x;          // 0..767
  const int w = cpp / 96, r = cpp % 96, s = r / 16, l15 = r % 16;
  const int g = s >> 1, jj = s & 1;
  const int orig = g * 256 + w * 32 + jj * 16 + l15;
  const float sc = (g < 2) ? S_RZ : S_N;
  const float* src = Whh + (size_t)orig * 256;
  f16* dst = out + (size_t)cpp * 256;
  dst[threadIdx.x] = (f16)(sc * src[threadIdx.x]);
}
__global__ void cvt_bias_g(const float* __restrict__ bih, const float* __restrict__ bhh,
                           float* __restrict__ bias_g, float* __restrict__ bhh_ng) {
  const int i = threadIdx.x + blockIdx.x * 256;   // 0..767
  {
    const int w = i / 96, r = i % 96, l15 = r / 6, s = r % 6;
    const int g = s >> 1, jj = s & 1;
    const int orig = g * 256 + w * 32 + jj * 16 + l15;
    const float sc = (g < 2) ? S_RZ : S_N;
    bias_g[i] = sc * (bih[orig] + ((g < 2) ? bhh[orig] : 0.f));
  }
  {
    const int w = i / 96, r = i % 96, s = r / 16, l15 = r % 16;
    const int g = s >> 1, jj = s & 1;
    const int orig = g * 256 + w * 32 + jj * 16 + l15;
    bhh_ng[i] = (g == 2) ? S_N * bhh[orig] : 0.f;
  }
}
// hist2 u32 [t][b][wv][16] (u32 = cols (wv*32+l15, wv*32+16+l15)) -> out f32 [b][t][256], masked
__global__ void expand_out(const unsigned* __restrict__ hist2, const int* __restrict__ clen,
                           float* __restrict__ out) {
  const int row = blockIdx.x;          // b*512+t
  const int b = row >> 9, t = row & 511;
  const int c = threadIdx.x;
  float v = 0.f;
  if (t < clen[b]) {
    const unsigned u = hist2[(size_t)(t * 16 + b) * 128 + (c >> 5) * 16 + (c & 15)];
    const f16x2 p = __builtin_bit_cast(f16x2, u);
    v = ((c & 31) < 16) ? (float)p.x : (float)p.y;
  }
  out[(size_t)row * 256 + c] = v;
}

// ---------------- MFMA f16 GEMM (128x128 tile, BK=32) ----------------
// A [M,K] f16 (lda), B [N,K] f16 (ldb) -> C[M,N]
// EPI 0: Cf = acc + bias[col] (f32)
// EPI 1: Ch = f16( Gin * sigmoid(acc + bias[col]) )
// EPI 3: Ch = f16(acc + bias[col]) scattered into xp48 [t][lane][4j][6s] layout
template <int EPI>
__global__ __launch_bounds__(256, 2) void gemm_nt(
    const f16* __restrict__ A, int lda,
    const f16* __restrict__ B, int ldb,
    const float* __restrict__ bias,
    float* __restrict__ Cf, f16* __restrict__ Ch, const f16* __restrict__ Gin,
    int M, int N, int K) {
  __shared__ f16 As[2][128 * 32];
  __shared__ f16 Bs[2][128 * 32];
  const int tiles_n = N >> 7;
  const int bm = (blockIdx.x / tiles_n) << 7;
  const int bn = (blockIdx.x % tiles_n) << 7;
  const int tid = threadIdx.x, wv = tid >> 6, lane = tid & 63;
  const int lr = lane & 15, lk = lane >> 4;
  const int wm = (wv >> 1) << 6, wn = (wv & 1) << 6;
  const int srow = lane >> 2;
  const int scol = (lane & 3) << 3;
  f32x4 acc[4][4] = {};

  auto stage = [&](int buf, int kt) {
    const int k0 = kt << 5;
    #pragma unroll
    for (int c = 0; c < 2; ++c) {
      const int row = ((wv * 2 + c) << 4) + srow;
      load_lds_16(A + (size_t)(bm + row) * lda + k0 + scol,
                  &As[buf][(wv * 2 + c) * 512]);
      load_lds_16(B + (size_t)(bn + row) * ldb + k0 + scol,
                  &Bs[buf][(wv * 2 + c) * 512]);
    }
  };

  const int NT = K >> 5;
  stage(0, 0);
  for (int kt = 0; kt < NT; ++kt) {
    const int buf = kt & 1;
    __syncthreads();
    if (kt + 1 < NT) stage(buf ^ 1, kt + 1);
    f16x8 af[4], bf[4];
    #pragma unroll
    for (int i = 0; i < 4; ++i)
      af[i] = *(const f16x8*)&As[buf][(wm + i * 16 + lr) * 32 + lk * 8];
    #pragma unroll
    for (int i = 0; i < 4; ++i)
      bf[i] = *(const f16x8*)&Bs[buf][(wn + i * 16 + lr) * 32 + lk * 8];
    #pragma unroll
    for (int mi = 0; mi < 4; ++mi)
      #pragma unroll
      for (int ni = 0; ni < 4; ++ni)
        acc[mi][ni] = __builtin_amdgcn_mfma_f32_16x16x32_f16(af[mi], bf[ni], acc[mi][ni], 0, 0, 0);
    __syncthreads();
  }

  const int crow0 = bm + wm + lk * 4;
  const int ccol0 = bn + wn + lr;
  #pragma unroll
  for (int mi = 0; mi < 4; ++mi) {
    #pragma unroll
    for (int ni = 0; ni < 4; ++ni) {
      const int col = ccol0 + ni * 16;
      const float bv = bias[col];
      #pragma unroll
      for (int j = 0; j < 4; ++j) {
        const int row = crow0 + mi * 16 + j;
        const float v = acc[mi][ni][j] + bv;
        if constexpr (EPI == 0) {
          Cf[(size_t)row * N + col] = v;
        } else if constexpr (EPI == 1) {
          const float rin = (float)Gin[(size_t)row * N + col];
          Ch[(size_t)row * N + col] = (f16)(rin * sigm(v));
        } else {
          // scatter into xp48: t=row&511, b=row>>9; slot = wv*64 + (b>>2)*16 + l15
          const int tt = row & 511, bb = row >> 9;
          const int wvv = col / 96, rr = col % 96;
          const int l15v = rr / 6, sv = rr % 6;
          Ch[(size_t)tt * 12288 + (wvv * 64 + (bb >> 2) * 16 + l15v) * 24 + (bb & 3) * 6 + sv] = (f16)v;
        }
      }
    }
  }
}

// ---------------- fused additive attention ----------------
__global__ __launch_bounds__(256) void attn_kernel(
    const float* __restrict__ cd, const float* __restrict__ qd,
    const float* __restrict__ qrep, const float* __restrict__ Ws,
    const float* __restrict__ bsp, const float* __restrict__ qmask,
    f16* __restrict__ rnn_h) {
  const int b = blockIdx.x >> 4;
  const int pc = blockIdx.x & 15;
  __shared__ f16 qd_s[64][264];
  __shared__ float ws_s[256];
  __shared__ float cd_s[256];
  __shared__ float sc_s[64];
  __shared__ float msk[64];
  const int tid = threadIdx.x;
  const float* qdb = qd + (size_t)b * 64 * 256;
  for (int i = tid; i < 64 * 256; i += 256) qd_s[i >> 8][i & 255] = (f16)qdb[i];
  ws_s[tid] = Ws[tid];
  if (tid < 64) msk[tid] = qmask[b * 64 + tid];
  __syncthreads();
  const float bsv = bsp[0];
  const float* qr = qrep + (size_t)b * 64 * 256;
  const int q = tid >> 2, l4 = tid & 3;
  for (int pi = 0; pi < 32; ++pi) {
    const int p = (pc << 5) + pi;
    cd_s[tid] = cd[((size_t)b * 512 + p) * 256 + tid];
    __syncthreads();
    float s = 0.f;
    #pragma unroll 2
    for (int jj = 0; jj < 16; ++jj) {
      const int h0 = (l4 << 2) + (jj << 4);
      #pragma unroll
      for (int e = 0; e < 4; ++e) {
        const int hh = h0 + e;
        s += ws_s[hh] * tanhfast(cd_s[hh] + (float)qd_s[q][hh]);
      }
    }
    s += __shfl_xor(s, 1);
    s += __shfl_xor(s, 2);
    if (l4 == 0) sc_s[q] = (msk[q] > 0.f) ? (s + bsv) : -1e30f;
    __syncthreads();
    if (tid < 64) {
      float v = sc_s[tid], m = v;
      #pragma unroll
      for (int o = 32; o; o >>= 1) m = fmaxf(m, __shfl_xor(m, o));
      const float e = __expf(v - m);
      float su = e;
      #pragma unroll
      for (int o = 32; o; o >>= 1) su += __shfl_xor(su, o);
      sc_s[tid] = e / su;
    }
    __syncthreads();
    float a = 0.f;
    #pragma unroll 8
    for (int q2 = 0; q2 < 64; ++q2) a = fmaf(sc_s[q2], qr[q2 * 256 + tid], a);
    rnn_h[(((size_t)b * 512 + p) << 9) + 256 + tid] = (f16)a;
  }
}

// ---------------- GRU: single block, MFMA recurrence ----------------
// M=16 batches, N=768 (8 waves x 6 subtiles of 16), K=256.
// Weights: subtiles s=0..3 resident in VGPRs (128 regs), s=4,5 in LDS (128 KB).
// h: double-buffered LDS [16][256] f16, row=batch b, byte ^= (b&7)<<4  (read row = l15).
// xp48: [512 t][512 lane][4 j][6 s] f16 -> dwordx3 prefetch.
// output: hist2 u32 [t][b][wv][16], one packed store per (lane,j).
__global__ __launch_bounds__(512) __attribute__((amdgpu_waves_per_eu(2, 2)))
void gru_mfma(
    const f16* __restrict__ xp48, const f16* __restrict__ Whh_g,
    const float* __restrict__ bhh_ng, unsigned* __restrict__ hist2) {
  const int tid = threadIdx.x;
  const int wv = tid >> 6, l = tid & 63, l15 = l & 15, lh = l >> 4;
  __shared__ char hs[2][8192];
  __shared__ char w_lds[131072];
  for (int i = tid; i < 2048; i += 512) {
    ((float*)hs[0])[i] = 0.f;
    ((float*)hs[1])[i] = 0.f;
  }

  // stage weight subtiles s=4,5 into LDS (per-wave private 16KB; each lane later
  // reads exactly the address it wrote, so any bijective swizzle is consistent)
  {
    char* wl = w_lds + wv * 16384;
    #pragma unroll
    for (int s2 = 0; s2 < 2; ++s2)
      #pragma unroll
      for (int kt = 0; kt < 8; ++kt) {
        f16x8 wt = *(const f16x8*)(Whh_g +
            (size_t)(wv * 96 + (4 + s2) * 16 + l15) * 256 + kt * 32 + lh * 8);
        *(f16x8*)(wl + s2 * 8192 + l15 * 512 +
                  ((kt * 64 + lh * 16) ^ ((l15 & 7) << 4))) = wt;
      }
  }

  // Whh B-fragments s=0..3 in VGPRs: row c'' = wv*96 + s*16 + l15, k = kt*32 + lh*8
  f16x8 wb[4][8];
  #pragma unroll
  for (int s = 0; s < 4; ++s)
    #pragma unroll
    for (int kt = 0; kt < 8; ++kt)
      wb[s][kt] = *(const f16x8*)(Whh_g + (size_t)(wv * 96 + s * 16 + l15) * 256 + kt * 32 + lh * 8);

  const float bhn0 = bhh_ng[wv * 96 + 64 + l15];
  const float bhn1 = bhh_ng[wv * 96 + 80 + l15];

  unsigned h2[4];
  #pragma unroll
  for (int j = 0; j < 4; ++j) h2[j] = 0u;

  const char* xbase = (const char*)xp48;
  char* hbase = (char*)hist2;
  unsigned xoff = (wv * 64 + l) * 48;                       // advances 24576 B/step
  unsigned hoff = lh * 2048 + wv * 64 + l15 * 4;            // advances 8192 B/step
  uint3 xq[4];
  #pragma unroll
  for (int j = 0; j < 4; ++j) xq[j] = *(const uint3*)(xbase + xoff + j * 12);
  xoff += 24576;
  __syncthreads();

  const char* wl = w_lds + wv * 16384;
  for (int t = 0; t < 512; ++t) {
    const int cur = t & 1;
    f32x4 acc[6];
    unsigned xnp[4];
    #pragma unroll
    for (int j = 0; j < 4; ++j) {
      f16x2 rr = __builtin_bit_cast(f16x2, xq[j].x);
      f16x2 zz = __builtin_bit_cast(f16x2, xq[j].y);
      acc[0][j] = (float)rr.x; acc[1][j] = (float)rr.y;
      acc[2][j] = (float)zz.x; acc[3][j] = (float)zz.y;
      xnp[j] = xq[j].z;
      acc[4][j] = bhn0;        acc[5][j] = bhn1;
    }
    if (t < 511) {                      // prefetch next step (hides under MFMA)
      #pragma unroll
      for (int j = 0; j < 4; ++j) xq[j] = *(const uint3*)(xbase + xoff + j * 12);
      xoff += 24576;
    }
    const char* hb = hs[cur];
    #pragma unroll
    for (int kt = 0; kt < 8; ++kt) {
      const int soff = (kt * 64 + lh * 16) ^ ((l15 & 7) << 4);
      f16x8 a = *(const f16x8*)(hb + l15 * 512 + soff);
      #pragma unroll
      for (int s = 0; s < 4; ++s)
        acc[s] = __builtin_amdgcn_mfma_f32_16x16x32_f16(a, wb[s][kt], acc[s], 0, 0, 0);
      f16x8 w4 = *(const f16x8*)(wl + l15 * 512 + soff);
      f16x8 w5 = *(const f16x8*)(wl + 8192 + l15 * 512 + soff);
      acc[4] = __builtin_amdgcn_mfma_f32_16x16x32_f16(a, w4, acc[4], 0, 0, 0);
      acc[5] = __builtin_amdgcn_mfma_f32_16x16x32_f16(a, w5, acc[5], 0, 0, 0);
    }
    char* hw = hs[cur ^ 1];
    #pragma unroll
    for (int j = 0; j < 4; ++j) {
      const int b = lh * 4 + j;
      const f16x2 hold = __builtin_bit_cast(f16x2, h2[j]);
      const f16x2 xn = __builtin_bit_cast(f16x2, xnp[j]);
      float hn0, hn1;
      {
        const float r = __builtin_amdgcn_rcpf(1.f + __builtin_amdgcn_exp2f(acc[0][j]));
        const float z = __builtin_amdgcn_rcpf(1.f + __builtin_amdgcn_exp2f(acc[2][j]));
        const float yy = fmaf(r, acc[4][j], (float)xn.x);
        const float n = fmaf(-2.f, __builtin_amdgcn_rcpf(1.f + __builtin_amdgcn_exp2f(yy)), 1.f);
        hn0 = fmaf(z, (float)hold.x - n, n);
      }
      {
        const float r = __builtin_amdgcn_rcpf(1.f + __builtin_amdgcn_exp2f(acc[1][j]));
        const float z = __builtin_amdgcn_rcpf(1.f + __builtin_amdgcn_exp2f(acc[3][j]));
        const float yy = fmaf(r, acc[5][j], (float)xn.y);
        const float n = fmaf(-2.f, __builtin_amdgcn_rcpf(1.f + __builtin_amdgcn_exp2f(yy)), 1.f);
        hn1 = fmaf(z, (float)hold.y - n, n);
      }
      const f16 h0h = (f16)hn0, h1h = (f16)hn1;
      h2[j] = __builtin_bit_cast(unsigned, (f16x2){h0h, h1h});
      *(unsigned*)(hbase + hoff + j * 512) = h2[j];
      *(f16*)(hw + ((b * 512 + (wv * 32 + l15) * 2) ^ ((b & 7) << 4))) = h0h;
      *(f16*)(hw + ((b * 512 + (wv * 32 + 16 + l15) * 2) ^ ((b & 7) << 4))) = h1h;
    }
    hoff += 8192;
    __syncthreads();
  }
}

// ---------------- launch ----------------
extern "C" void kernel_launch(void* const* d_in, const int* in_sizes, int n_in,
                              void* d_out, int out_size, void* d_ws, size_t ws_size,
                              hipStream_t stream) {
  const float* ctx   = (const float*)d_in[0];
  const float* qrep  = (const float*)d_in[1];
  const int*   clen  = (const int*)d_in[2];
  const float* qmask = (const float*)d_in[3];
  const float* Wc    = (const float*)d_in[4];
  const float* bc    = (const float*)d_in[5];
  const float* Wq    = (const float*)d_in[6];
  const float* bq    = (const float*)d_in[7];
  const float* Ws    = (const float*)d_in[8];
  const float* bs    = (const float*)d_in[9];
  const float* Wg    = (const float*)d_in[10];
  const float* bg    = (const float*)d_in[11];
  const float* Wih   = (const float*)d_in[12];
  const float* Whh   = (const float*)d_in[13];
  const float* bih   = (const float*)d_in[14];
  const float* bhh   = (const float*)d_in[15];
  float* out = (float*)d_out;

  char* w = (char*)d_ws;
  auto alloc = [&](size_t bytes) -> void* {
    void* p = (void*)w;
    w += (bytes + 255) & ~(size_t)255;
    return p;
  };
  const int M = kB * kLC;                 // 8192
  // hist2 (4 MB) aliases cd (8 MB) — cd is dead after attn_kernel.
  float* cd     = (float*)alloc((size_t)M * 256 * 4);
  float* qd     = (float*)alloc((size_t)1024 * 256 * 4);
  f16* rnn_h    = (f16*)alloc((size_t)M * 512 * 2);
  f16* q_h      = (f16*)alloc((size_t)1024 * 256 * 2);
  f16* g_h      = (f16*)alloc((size_t)M * 512 * 2);
  f16* xp48     = (f16*)alloc((size_t)512 * 12288 * 2);
  f16* Wct_h    = (f16*)alloc((size_t)256 * 256 * 2);
  f16* Wqt_h    = (f16*)alloc((size_t)256 * 256 * 2);
  f16* Wgt_h    = (f16*)alloc((size_t)512 * 512 * 2);
  f16* Wih_g    = (f16*)alloc((size_t)768 * 512 * 2);
  f16* Whh_g    = (f16*)alloc((size_t)768 * 256 * 2);
  float* bias_g = (float*)alloc(768 * 4);
  float* bhh_ng = (float*)alloc(768 * 4);
  unsigned* hist2 = (unsigned*)cd;        // alias (4 MB <= 8 MB, disjoint lifetime)

  // conversions
  cvt_ctx   <<<M, 256, 0, stream>>>(ctx, rnn_h);
  cvt_flat  <<<1024, 256, 0, stream>>>(qrep, q_h, 1024 * 256);
  cvt_tr    <<<64, 256, 0, stream>>>(Wc, Wct_h, 256, 256);
  cvt_tr    <<<64, 256, 0, stream>>>(Wq, Wqt_h, 256, 256);
  cvt_tr    <<<256, 256, 0, stream>>>(Wg, Wgt_h, 512, 512);
  cvt_wih_g <<<768, 256, 0, stream>>>(Wih, Wih_g);
  cvt_whh_g <<<768, 256, 0, stream>>>(Whh, Whh_g);
  cvt_bias_g<<<3, 256, 0, stream>>>(bih, bhh, bias_g, bhh_ng);

  // cd = ctx @ Wc + bc ; qd = q @ Wq + bq
  gemm_nt<0><<<(M / 128) * (256 / 128), 256, 0, stream>>>(
      rnn_h, 512, Wct_h, 256, bc, cd, nullptr, nullptr, M, 256, 256);
  gemm_nt<0><<<(1024 / 128) * (256 / 128), 256, 0, stream>>>(
      q_h, 256, Wqt_h, 256, bq, qd, nullptr, nullptr, 1024, 256, 256);

  // attention -> rnn_h[:, 256:512]
  attn_kernel<<<256, 256, 0, stream>>>(cd, qd, qrep, Ws, bs, qmask, rnn_h);

  // g = rnn_in * sigmoid(rnn_in @ Wg + bg)
  gemm_nt<1><<<(M / 128) * (512 / 128), 256, 0, stream>>>(
      rnn_h, 512, Wgt_h, 512, bg, nullptr, g_h, rnn_h, M, 512, 512);

  // xp48 = f16( g @ Wih_g.T + bias_g )  scattered into [t][lane][48B] layout
  gemm_nt<3><<<(M / 128) * (768 / 128), 256, 0, stream>>>(
      g_h, 512, Wih_g, 512, bias_g, nullptr, xp48, nullptr, M, 768, 512);

  // GRU recurrence (single block, MFMA, weights in VGPRs+LDS)
  gru_mfma<<<1, 512, 0, stream>>>(xp48, Whh_g, bhh_ng, hist2);

  // hist2 -> out (f32, masked)
  expand_out<<<M, 256, 0, stream>>>(hist2, clen, out);
}